// Round 6
// baseline (4160.268 us; speedup 1.0000x reference)
//
#include <hip/hip_runtime.h>
#include <stdint.h>

typedef __attribute__((ext_vector_type(8))) short short8;
typedef __attribute__((ext_vector_type(4))) float f32x4;
typedef unsigned short bfraw;

#define Bn 64
#define Tn 256
#define En 512
#define Hn 512
#define TAGSn 50

__device__ __forceinline__ bfraw f2bf(float f) {
  union { float f; uint32_t u; } v; v.f = f;
  uint32_t u = v.u;
  return (bfraw)((u + 0x7FFFu + ((u >> 16) & 1u)) >> 16);   // RNE
}
__device__ __forceinline__ float bf2f(bfraw h) {
  union { uint32_t u; float f; } v; v.u = ((uint32_t)h) << 16;
  return v.f;
}
__device__ __forceinline__ float sigm(float x) { return 1.f / (1.f + __expf(-x)); }
__device__ __forceinline__ float tanh_fast(float x) { return 1.f - 2.f / (__expf(2.f * x) + 1.f); }

// ---------------- prep kernels ----------------
__global__ void k_cvt(const float* __restrict__ s, bfraw* __restrict__ d, int n) {
  int i = blockIdx.x * 256 + threadIdx.x;
  if (i < n) d[i] = f2bf(s[i]);
}

__global__ void k_bias(const float* __restrict__ a, const float* __restrict__ b,
                       float* __restrict__ d, int n) {
  int i = blockIdx.x * 256 + threadIdx.x;
  if (i < n) d[i] = a[i] + b[i];
}

__global__ void k_fcpad(const float* __restrict__ w, const float* __restrict__ b,
                        bfraw* __restrict__ wd, float* __restrict__ bd) {
  int i = blockIdx.x * 256 + threadIdx.x;   // 128*1024
  int row = i >> 10, col = i & 1023;
  wd[i] = (row < TAGSn) ? f2bf(w[row * 1024 + col]) : (bfraw)0;
  if (i < 128) bd[i] = (i < TAGSn) ? b[i] : 0.f;
}

// embedding gather: xs[t][b][e] = bf16(emb[x[b][t]][e])
__global__ void k_embed(const int* __restrict__ x, const float* __restrict__ emb,
                        bfraw* __restrict__ xs) {
  int i = blockIdx.x * 256 + threadIdx.x;   // 16384 tokens * 64 chunks
  int tok = i >> 6, c = i & 63;
  int t = tok >> 6, b = tok & 63;
  int vid = x[b * Tn + t];
  const float* src = emb + (size_t)vid * En + c * 8;
  float4 v0 = *(const float4*)(src);
  float4 v1 = *(const float4*)(src + 4);
  short8 o;
  o[0] = (short)f2bf(v0.x); o[1] = (short)f2bf(v0.y);
  o[2] = (short)f2bf(v0.z); o[3] = (short)f2bf(v0.w);
  o[4] = (short)f2bf(v1.x); o[5] = (short)f2bf(v1.y);
  o[6] = (short)f2bf(v1.z); o[7] = (short)f2bf(v1.w);
  *(short8*)(xs + (size_t)tok * En + c * 8) = o;
}

// ---------------- GEMM: C[crow][col] = A[row][:] . Bm[col][:] + bias[col]  (bf16, B^T) ----
// 128x128 tile, BK=64, 4 waves (2x2 quadrants), reg-staged LDS with XOR swizzle.
// MODE 0: C bf16 row-major; rev=1 maps local row -> (127-(row>>6))*64+(row&63) (bw gate chunks).
// MODE 1: FC epilogue -> FP32 out[b][t][tag], col<50.  (reference output dtype is fp32!)
template <int MODE>
__global__ __launch_bounds__(256) void k_gemm(const bfraw* __restrict__ A,
                                              const bfraw* __restrict__ Bm,
                                              const float* __restrict__ bias,
                                              void* __restrict__ Cv, int K, int ldc, int rev) {
  __shared__ __align__(16) bfraw lA[128 * 64];
  __shared__ __align__(16) bfraw lB[128 * 64];
  const int tid = threadIdx.x;
  const int w = tid >> 6, l = tid & 63;
  const int wr = w >> 1, wc = w & 1;
  const size_t m0 = (size_t)blockIdx.x * 128;
  const size_t n0 = (size_t)blockIdx.y * 128;
  const int lr = l & 15;
  const int lk = (l >> 4) * 8;

  f32x4 acc[4][4];
#pragma unroll
  for (int i = 0; i < 4; i++)
#pragma unroll
    for (int jj = 0; jj < 4; jj++) acc[i][jj] = (f32x4){0.f, 0.f, 0.f, 0.f};

  for (int k0 = 0; k0 < K; k0 += 64) {
    short8 ra[4], rb[4];
#pragma unroll
    for (int c = 0; c < 4; c++) {
      int flat = c * 256 + tid;
      int row = flat >> 3, cc = flat & 7;
      ra[c] = *(const short8*)(A + (m0 + row) * K + k0 + cc * 8);
      rb[c] = *(const short8*)(Bm + (n0 + row) * K + k0 + cc * 8);
    }
    __syncthreads();   // previous tile's fragment reads complete
#pragma unroll
    for (int c = 0; c < 4; c++) {
      int flat = c * 256 + tid;
      int row = flat >> 3, cc = flat & 7;
      int off = row * 64 + ((cc * 8) ^ ((row & 7) << 3));   // swizzled write
      *(short8*)(lA + off) = ra[c];
      *(short8*)(lB + off) = rb[c];
    }
    __syncthreads();
#pragma unroll
    for (int kk = 0; kk < 2; ++kk) {
      short8 aq[4], bq[4];
      int ks = kk * 32 + lk;
#pragma unroll
      for (int i = 0; i < 4; i++) {
        int row = wr * 64 + i * 16 + lr;
        aq[i] = *(const short8*)(lA + row * 64 + (ks ^ ((row & 7) << 3)));
      }
#pragma unroll
      for (int jj = 0; jj < 4; jj++) {
        int row = wc * 64 + jj * 16 + lr;
        bq[jj] = *(const short8*)(lB + row * 64 + (ks ^ ((row & 7) << 3)));
      }
#pragma unroll
      for (int i = 0; i < 4; i++)
#pragma unroll
        for (int jj = 0; jj < 4; jj++)
          acc[i][jj] = __builtin_amdgcn_mfma_f32_16x16x32_bf16(aq[i], bq[jj], acc[i][jj], 0, 0, 0);
    }
  }

  const int lq = (l >> 4) * 4;
#pragma unroll
  for (int i = 0; i < 4; i++)
#pragma unroll
    for (int jj = 0; jj < 4; jj++) {
#pragma unroll
      for (int r = 0; r < 4; r++) {
        size_t row = m0 + wr * 64 + i * 16 + lq + r;     // C/D: row=(l>>4)*4+reg
        size_t col = n0 + wc * 64 + jj * 16 + lr;        //      col=l&15
        float v = acc[i][jj][r] + bias[col];
        if (MODE == 0) {
          size_t crow = rev ? ((size_t)(127 - (int)(row >> 6)) * 64 + (row & 63)) : row;
          ((bfraw*)Cv)[crow * ldc + col] = f2bf(v);
        } else {
          size_t tt = row >> 6, bb = row & 63;           // m = t*64 + b
          if ((int)col < TAGSn) ((float*)Cv)[(bb * Tn + tt) * TAGSn + col] = v;  // FP32 out
        }
      }
    }
}

// ---------------- LSTM step (one launch per timestep) ----------------
// grid = 64: d = blk>>5 (0 fw, 1 bw), j = blk&31 owns h-cols [j*16, j*16+16).
// wave w computes gate w's pre-activations for all 64 batches via MFMA.
// Gs is step-major: row (srow*64+b) holds gates for this step in BOTH directions.
__global__ __launch_bounds__(256) void k_lstm_step(const bfraw* __restrict__ Gs,
                                                   const bfraw* __restrict__ Whh,
                                                   bfraw* __restrict__ out,
                                                   float* __restrict__ cbuf, int s, int srow) {
  __shared__ __align__(16) bfraw hl[64 * 512];   // 64 KB, XOR-swizzled
  __shared__ float gl[4 * 64 * 16];              // 16 KB gate exchange
  const int blk = blockIdx.x;
  const int d = blk >> 5, j = blk & 31;
  const int tid = threadIdx.x;
  const int w = tid >> 6, l = tid & 63;
  const int t = d ? (Tn - 1 - s) : s;
  const int tprev = d ? (t + 1) : (t - 1);

  if (s > 0) {   // stage h_prev[64][512] (bf16 half-slab of layer output)
#pragma unroll
    for (int c = 0; c < 16; ++c) {
      int flat = c * 256 + tid;
      int row = flat >> 6;   // batch
      int cc = flat & 63;    // 8-short chunk within 512
      short8 v = *(const short8*)(out + (size_t)(tprev * Bn + row) * 1024 + d * 512 + cc * 8);
      *(short8*)(hl + row * 512 + ((cc * 8) ^ ((row & 7) << 3))) = v;
    }
  }
  __syncthreads();

  f32x4 acc[4];
#pragma unroll
  for (int i = 0; i < 4; i++) acc[i] = (f32x4){0.f, 0.f, 0.f, 0.f};

  if (s > 0) {
    const bfraw* Wd = Whh + ((size_t)d * 2048 + w * 512 + j * 16) * 512;
    const int lrr = l & 15, lk = (l >> 4) * 8;
#pragma unroll
    for (int kk = 0; kk < 16; ++kk) {
      short8 bq = *(const short8*)(Wd + (size_t)lrr * 512 + kk * 32 + lk);   // B-frag from L2
#pragma unroll
      for (int mt = 0; mt < 4; ++mt) {
        int row = mt * 16 + lrr;
        int ks = kk * 32 + lk;
        short8 aq = *(const short8*)(hl + row * 512 + (ks ^ ((row & 7) << 3)));
        acc[mt] = __builtin_amdgcn_mfma_f32_16x16x32_bf16(aq, bq, acc[mt], 0, 0, 0);
      }
    }
  }

  {  // add input-projection term, publish pre-activations to LDS
    const int lrr = l & 15, lq = (l >> 4) * 4;
#pragma unroll
    for (int mt = 0; mt < 4; ++mt)
#pragma unroll
      for (int r = 0; r < 4; ++r) {
        int bb = mt * 16 + lq + r;
        float v = acc[mt][r] +
                  bf2f(Gs[(size_t)(srow * Bn + bb) * 4096 + d * 2048 + w * 512 + j * 16 + lrr]);
        gl[(w * 64 + bb) * 16 + lrr] = v;
      }
  }
  __syncthreads();

  {  // gate combine: wave w owns batches [w*16, w*16+16)
    const int col = l & 15;
#pragma unroll
    for (int r = 0; r < 4; ++r) {
      int bb = w * 16 + (l >> 4) + r * 4;
      float vi = gl[(0 * 64 + bb) * 16 + col];
      float vf = gl[(1 * 64 + bb) * 16 + col];
      float vg = gl[(2 * 64 + bb) * 16 + col];
      float vo = gl[(3 * 64 + bb) * 16 + col];
      float* cp = cbuf + ((size_t)d * Bn + bb) * 512 + j * 16 + col;
      float c = (s > 0) ? *cp : 0.f;
      c = sigm(vf) * c + sigm(vi) * tanh_fast(vg);
      float h = sigm(vo) * tanh_fast(c);
      *cp = c;
      out[(size_t)(t * Bn + bb) * 1024 + d * 512 + j * 16 + col] = f2bf(h);
    }
  }
}

// ---------------- launcher ----------------
extern "C" void kernel_launch(void* const* d_in, const int* in_sizes, int n_in,
                              void* d_out, int out_size, void* d_ws, size_t ws_size,
                              hipStream_t stream) {
  const int*   x      = (const int*)d_in[0];
  const float* emb    = (const float*)d_in[2];
  const float* Wih_f1 = (const float*)d_in[3];
  const float* Whh_f1 = (const float*)d_in[4];
  const float* bih_f1 = (const float*)d_in[5];
  const float* bhh_f1 = (const float*)d_in[6];
  const float* Wih_b1 = (const float*)d_in[7];
  const float* Whh_b1 = (const float*)d_in[8];
  const float* bih_b1 = (const float*)d_in[9];
  const float* bhh_b1 = (const float*)d_in[10];
  const float* Wih_f2 = (const float*)d_in[11];
  const float* Whh_f2 = (const float*)d_in[12];
  const float* bih_f2 = (const float*)d_in[13];
  const float* bhh_f2 = (const float*)d_in[14];
  const float* Wih_b2 = (const float*)d_in[15];
  const float* Whh_b2 = (const float*)d_in[16];
  const float* bih_b2 = (const float*)d_in[17];
  const float* bhh_b2 = (const float*)d_in[18];
  const float* fc_W   = (const float*)d_in[19];
  const float* fc_b   = (const float*)d_in[20];

  char* ws = (char*)d_ws;
  // ws layout (bytes) — peak 120 MB
  bfraw* Wcat1 = (bfraw*)(ws + 0);            // 4 MB   [4096][512]
  bfraw* Whh1  = (bfraw*)(ws + 4194304);      // 4 MB   [2][2048][512]
  bfraw* Wcat2 = (bfraw*)(ws + 8388608);      // 8 MB   [4096][1024]
  bfraw* Whh2  = (bfraw*)(ws + 16777216);     // 4 MB
  bfraw* fcW   = (bfraw*)(ws + 20971520);     // 256 KB [128][1024]
  float* bias1 = (float*)(ws + 21233664);     // 16 KB
  float* bias2 = (float*)(ws + 21250048);     // 16 KB
  float* fcb   = (float*)(ws + 21266432);     // 512 B
  float* cbuf  = (float*)(ws + 21266944);     // 256 KB [2][64][512] f32
  bfraw* out1  = (bfraw*)(ws + 22020096);     // 33.5 MB [256][64][1024]
  bfraw* out2  = (bfraw*)(ws + 56623104);     // 33.5 MB (xs aliases first 16 MB)
  bfraw* xs    = out2;                        // 16 MB  [16384][512] — dead before out2 writes
  bfraw* Gs    = (bfraw*)(ws + 92274688);     // 33.5 MB [128][64][4096] step-major chunk
  float* outp  = (float*)d_out;               // FP32 logits [B][T][50]

  auto cvt = [&](const float* s, bfraw* dp, int n) {
    k_cvt<<<(n + 255) / 256, 256, 0, stream>>>(s, dp, n);
  };
  cvt(Wih_f1, Wcat1, 2048 * 512);
  cvt(Wih_b1, Wcat1 + 2048 * 512, 2048 * 512);
  cvt(Whh_f1, Whh1, 2048 * 512);
  cvt(Whh_b1, Whh1 + 2048 * 512, 2048 * 512);
  cvt(Wih_f2, Wcat2, 2048 * 1024);
  cvt(Wih_b2, Wcat2 + 2048 * 1024, 2048 * 1024);
  cvt(Whh_f2, Whh2, 2048 * 512);
  cvt(Whh_b2, Whh2 + 2048 * 512, 2048 * 512);
  k_bias<<<8, 256, 0, stream>>>(bih_f1, bhh_f1, bias1, 2048);
  k_bias<<<8, 256, 0, stream>>>(bih_b1, bhh_b1, bias1 + 2048, 2048);
  k_bias<<<8, 256, 0, stream>>>(bih_f2, bhh_f2, bias2, 2048);
  k_bias<<<8, 256, 0, stream>>>(bih_b2, bhh_b2, bias2 + 2048, 2048);
  k_fcpad<<<512, 256, 0, stream>>>(fc_W, fc_b, fcW, fcb);

  k_embed<<<4096, 256, 0, stream>>>(x, emb, xs);

  // ---- per layer: 2 T-chunks; per chunk: fw-gate GEMM + row-reversed bw-gate GEMM + 128 steps
  auto run_layer = [&](const bfraw* inL, int K, const bfraw* Wcat, const float* biasv,
                       const bfraw* WhhL, bfraw* outL) {
    for (int c = 0; c < 2; ++c) {
      // fw gates: A rows t in [c*128, c*128+128) -> Gs local row = t - c*128
      k_gemm<0><<<dim3(64, 16), 256, 0, stream>>>(
          inL + (size_t)c * 8192 * K, Wcat, biasv, Gs, K, 4096, 0);
      // bw gates: A rows t in [(1-c)*128, ...) -> Gs local row = 127 - (t - (1-c)*128)
      k_gemm<0><<<dim3(64, 16), 256, 0, stream>>>(
          inL + (size_t)(1 - c) * 8192 * K, Wcat + (size_t)2048 * K, biasv + 2048,
          Gs + 2048, K, 4096, 1);
      for (int s = c * 128; s < c * 128 + 128; ++s)
        k_lstm_step<<<64, 256, 0, stream>>>(Gs, WhhL, outL, cbuf, s, s - c * 128);
    }
  };

  run_layer(xs, 512, Wcat1, bias1, Whh1, out1);    // layer 1
  run_layer(out1, 1024, Wcat2, bias2, Whh2, out2); // layer 2

  // FC -> FP32 logits [B][T][50]
  k_gemm<1><<<dim3(128, 1), 256, 0, stream>>>(out2, fcW, fcb, outp, 1024, 0, 0);
}

// Round 9
// 4091.167 us; speedup vs baseline: 1.0169x; 1.0169x over previous
//
#include <hip/hip_runtime.h>
#include <stdint.h>

typedef __attribute__((ext_vector_type(8))) short short8;
typedef __attribute__((ext_vector_type(4))) float f32x4;
typedef unsigned short bfraw;

#define Bn 64
#define Tn 256
#define En 512
#define Hn 512
#define TAGSn 50

__device__ __forceinline__ bfraw f2bf(float f) {
  union { float f; uint32_t u; } v; v.f = f;
  uint32_t u = v.u;
  return (bfraw)((u + 0x7FFFu + ((u >> 16) & 1u)) >> 16);   // RNE
}
__device__ __forceinline__ float bf2f(bfraw h) {
  union { uint32_t u; float f; } v; v.u = ((uint32_t)h) << 16;
  return v.f;
}
__device__ __forceinline__ float sigm(float x) { return 1.f / (1.f + __expf(-x)); }
__device__ __forceinline__ float tanh_fast(float x) { return 1.f - 2.f / (__expf(2.f * x) + 1.f); }

// ---------------- prep kernels ----------------
__global__ void k_cvt(const float* __restrict__ s, bfraw* __restrict__ d, int n) {
  int i = blockIdx.x * 256 + threadIdx.x;
  if (i < n) d[i] = f2bf(s[i]);
}

__global__ void k_bias(const float* __restrict__ a, const float* __restrict__ b,
                       float* __restrict__ d, int n) {
  int i = blockIdx.x * 256 + threadIdx.x;
  if (i < n) d[i] = a[i] + b[i];
}

__global__ void k_fcpad(const float* __restrict__ w, const float* __restrict__ b,
                        bfraw* __restrict__ wd, float* __restrict__ bd) {
  int i = blockIdx.x * 256 + threadIdx.x;   // 128*1024
  int row = i >> 10, col = i & 1023;
  wd[i] = (row < TAGSn) ? f2bf(w[row * 1024 + col]) : (bfraw)0;
  if (i < 128) bd[i] = (i < TAGSn) ? b[i] : 0.f;
}

// embedding gather: xs[t][b][e] = bf16(emb[x[b][t]][e])
__global__ void k_embed(const int* __restrict__ x, const float* __restrict__ emb,
                        bfraw* __restrict__ xs) {
  int i = blockIdx.x * 256 + threadIdx.x;   // 16384 tokens * 64 chunks
  int tok = i >> 6, c = i & 63;
  int t = tok >> 6, b = tok & 63;
  int vid = x[b * Tn + t];
  const float* src = emb + (size_t)vid * En + c * 8;
  float4 v0 = *(const float4*)(src);
  float4 v1 = *(const float4*)(src + 4);
  short8 o;
  o[0] = (short)f2bf(v0.x); o[1] = (short)f2bf(v0.y);
  o[2] = (short)f2bf(v0.z); o[3] = (short)f2bf(v0.w);
  o[4] = (short)f2bf(v1.x); o[5] = (short)f2bf(v1.y);
  o[6] = (short)f2bf(v1.z); o[7] = (short)f2bf(v1.w);
  *(short8*)(xs + (size_t)tok * En + c * 8) = o;
}

// ---------------- GEMM: C[row][col] = A[row][:] . Bm[col][:] + bias[col]  (bf16, B^T) ----
// 128x128 tile, BK=64, 4 waves (2x2 quadrants), reg-staged LDS with XOR swizzle.
// MODE 0: C bf16 row-major [M][ldc].  MODE 1: FC epilogue -> FP32 out[b][t][tag], col<50.
template <int MODE>
__global__ __launch_bounds__(256) void k_gemm(const bfraw* __restrict__ A,
                                              const bfraw* __restrict__ Bm,
                                              const float* __restrict__ bias,
                                              void* __restrict__ Cv, int K, int ldc) {
  __shared__ __align__(16) bfraw lA[128 * 64];
  __shared__ __align__(16) bfraw lB[128 * 64];
  const int tid = threadIdx.x;
  const int w = tid >> 6, l = tid & 63;
  const int wr = w >> 1, wc = w & 1;
  const size_t m0 = (size_t)blockIdx.x * 128;
  const size_t n0 = (size_t)blockIdx.y * 128;
  const int lr = l & 15;
  const int lk = (l >> 4) * 8;

  f32x4 acc[4][4];
#pragma unroll
  for (int i = 0; i < 4; i++)
#pragma unroll
    for (int jj = 0; jj < 4; jj++) acc[i][jj] = (f32x4){0.f, 0.f, 0.f, 0.f};

  for (int k0 = 0; k0 < K; k0 += 64) {
    short8 ra[4], rb[4];
#pragma unroll
    for (int c = 0; c < 4; c++) {
      int flat = c * 256 + tid;
      int row = flat >> 3, cc = flat & 7;
      ra[c] = *(const short8*)(A + (m0 + row) * K + k0 + cc * 8);
      rb[c] = *(const short8*)(Bm + (n0 + row) * K + k0 + cc * 8);
    }
    __syncthreads();   // previous tile's fragment reads complete
#pragma unroll
    for (int c = 0; c < 4; c++) {
      int flat = c * 256 + tid;
      int row = flat >> 3, cc = flat & 7;
      int off = row * 64 + ((cc * 8) ^ ((row & 7) << 3));   // swizzled write
      *(short8*)(lA + off) = ra[c];
      *(short8*)(lB + off) = rb[c];
    }
    __syncthreads();
#pragma unroll
    for (int kk = 0; kk < 2; ++kk) {
      short8 aq[4], bq[4];
      int ks = kk * 32 + lk;
#pragma unroll
      for (int i = 0; i < 4; i++) {
        int row = wr * 64 + i * 16 + lr;
        aq[i] = *(const short8*)(lA + row * 64 + (ks ^ ((row & 7) << 3)));
      }
#pragma unroll
      for (int jj = 0; jj < 4; jj++) {
        int row = wc * 64 + jj * 16 + lr;
        bq[jj] = *(const short8*)(lB + row * 64 + (ks ^ ((row & 7) << 3)));
      }
#pragma unroll
      for (int i = 0; i < 4; i++)
#pragma unroll
        for (int jj = 0; jj < 4; jj++)
          acc[i][jj] = __builtin_amdgcn_mfma_f32_16x16x32_bf16(aq[i], bq[jj], acc[i][jj], 0, 0, 0);
    }
  }

  const int lq = (l >> 4) * 4;
#pragma unroll
  for (int i = 0; i < 4; i++)
#pragma unroll
    for (int jj = 0; jj < 4; jj++) {
#pragma unroll
      for (int r = 0; r < 4; r++) {
        size_t row = m0 + wr * 64 + i * 16 + lq + r;     // C/D: row=(l>>4)*4+reg
        size_t col = n0 + wc * 64 + jj * 16 + lr;        //      col=l&15
        float v = acc[i][jj][r] + bias[col];
        if (MODE == 0) {
          ((bfraw*)Cv)[row * ldc + col] = f2bf(v);
        } else {
          size_t tt = row >> 6, bb = row & 63;           // m = t*64 + b
          if ((int)col < TAGSn) ((float*)Cv)[(bb * Tn + tt) * TAGSn + col] = v;  // FP32 out
        }
      }
    }
}

// ---------------- persistent LSTM recurrence (all 256 steps, one launch per layer) --------
// grid = 64 blocks: d = blk>>5 (0 fw, 1 bw), j = blk&31 owns h-cols [j*16, j*16+16).
// Wave w = gate w. Whh fragments hoisted into registers once; c-state in registers.
// Per-direction 32-block barrier via monotonic device-scope counter bar[d] (pre-zeroed).
__global__ __launch_bounds__(256) void k_lstm_seq(const bfraw* __restrict__ G,
                                                  const bfraw* __restrict__ Whh,
                                                  bfraw* __restrict__ out,
                                                  int* __restrict__ bar) {
  __shared__ __align__(16) bfraw hl[64 * 512];   // 64 KB, XOR-swizzled h_prev
  __shared__ float gl[4 * 64 * 16];              // 16 KB gate exchange
  const int blk = blockIdx.x;
  const int d = blk >> 5, j = blk & 31;
  const int tid = threadIdx.x;
  const int w = tid >> 6, l = tid & 63;
  const int lr = l & 15, lk = (l >> 4) * 8, lq = (l >> 4) * 4;
  int* cnt = bar + d;

  // hoist Whh B-fragments into registers (64 VGPRs): rows d*2048+w*512+j*16+lr, all K
  short8 bq[16];
  {
    const bfraw* Wd = Whh + ((size_t)(d * 2048 + w * 512 + j * 16 + lr)) * 512;
#pragma unroll
    for (int kk = 0; kk < 16; ++kk) bq[kk] = *(const short8*)(Wd + kk * 32 + lk);
  }

  float creg[4] = {0.f, 0.f, 0.f, 0.f};   // c-state for this thread's 4 (b,col) pairs

  for (int s = 0; s < Tn; ++s) {
    const int t = d ? (Tn - 1 - s) : s;
    const int tprev = d ? (t + 1) : (t - 1);

    // prefetch input-projection term (independent of h) before the barrier wait
    float gpre[4][4];
#pragma unroll
    for (int mt = 0; mt < 4; ++mt)
#pragma unroll
      for (int r = 0; r < 4; ++r) {
        int bb = mt * 16 + lq + r;
        gpre[mt][r] =
            bf2f(G[((size_t)t * Bn + bb) * 4096 + d * 2048 + w * 512 + j * 16 + lr]);
      }

    if (s > 0) {
      if (tid == 0) {   // wait until all 32 dir-d blocks finished step s-1
        while (__hip_atomic_load(cnt, __ATOMIC_ACQUIRE, __HIP_MEMORY_SCOPE_AGENT) < 32 * s)
          __builtin_amdgcn_s_sleep(2);
      }
      __syncthreads();
      // stage h(tprev)[64][512] -> LDS swizzled
#pragma unroll
      for (int c = 0; c < 16; ++c) {
        int flat = c * 256 + tid;
        int row = flat >> 6, cc = flat & 63;
        short8 v = *(const short8*)(out + ((size_t)tprev * Bn + row) * 1024 + d * 512 + cc * 8);
        *(short8*)(hl + row * 512 + ((cc * 8) ^ ((row & 7) << 3))) = v;
      }
      __syncthreads();
    }

    f32x4 acc[4];
#pragma unroll
    for (int i = 0; i < 4; i++) acc[i] = (f32x4){0.f, 0.f, 0.f, 0.f};

    if (s > 0) {
#pragma unroll
      for (int kk = 0; kk < 16; ++kk) {
        int ks = kk * 32 + lk;
#pragma unroll
        for (int mt = 0; mt < 4; ++mt) {
          int row = mt * 16 + lr;
          short8 aq = *(const short8*)(hl + row * 512 + (ks ^ ((row & 7) << 3)));
          acc[mt] = __builtin_amdgcn_mfma_f32_16x16x32_bf16(aq, bq[kk], acc[mt], 0, 0, 0);
        }
      }
    }

    // publish pre-activations (recurrent + input-projection) to LDS
#pragma unroll
    for (int mt = 0; mt < 4; ++mt)
#pragma unroll
      for (int r = 0; r < 4; ++r) {
        int bb = mt * 16 + lq + r;
        gl[(w * 64 + bb) * 16 + lr] = acc[mt][r] + gpre[mt][r];
      }
    __syncthreads();

    // gate combine: wave w owns batches [w*16, w*16+16)
#pragma unroll
    for (int r = 0; r < 4; ++r) {
      int bb = w * 16 + (l >> 4) + r * 4;
      int col = l & 15;
      float vi = gl[(0 * 64 + bb) * 16 + col];
      float vf = gl[(1 * 64 + bb) * 16 + col];
      float vg = gl[(2 * 64 + bb) * 16 + col];
      float vo = gl[(3 * 64 + bb) * 16 + col];
      float cv = creg[r];
      cv = sigm(vf) * cv + sigm(vi) * tanh_fast(vg);
      float h = sigm(vo) * tanh_fast(cv);
      creg[r] = cv;
      out[((size_t)t * Bn + bb) * 1024 + d * 512 + j * 16 + col] = f2bf(h);
    }

    __syncthreads();   // all waves' h stores drained (vmcnt 0) before signaling
    if (tid == 0)
      __hip_atomic_fetch_add(cnt, 1, __ATOMIC_RELEASE, __HIP_MEMORY_SCOPE_AGENT);
  }
}

// ---------------- launcher ----------------
extern "C" void kernel_launch(void* const* d_in, const int* in_sizes, int n_in,
                              void* d_out, int out_size, void* d_ws, size_t ws_size,
                              hipStream_t stream) {
  const int*   x      = (const int*)d_in[0];
  const float* emb    = (const float*)d_in[2];
  const float* Wih_f1 = (const float*)d_in[3];
  const float* Whh_f1 = (const float*)d_in[4];
  const float* bih_f1 = (const float*)d_in[5];
  const float* bhh_f1 = (const float*)d_in[6];
  const float* Wih_b1 = (const float*)d_in[7];
  const float* Whh_b1 = (const float*)d_in[8];
  const float* bih_b1 = (const float*)d_in[9];
  const float* bhh_b1 = (const float*)d_in[10];
  const float* Wih_f2 = (const float*)d_in[11];
  const float* Whh_f2 = (const float*)d_in[12];
  const float* bih_f2 = (const float*)d_in[13];
  const float* bhh_f2 = (const float*)d_in[14];
  const float* Wih_b2 = (const float*)d_in[15];
  const float* Whh_b2 = (const float*)d_in[16];
  const float* bih_b2 = (const float*)d_in[17];
  const float* bhh_b2 = (const float*)d_in[18];
  const float* fc_W   = (const float*)d_in[19];
  const float* fc_b   = (const float*)d_in[20];

  char* ws = (char*)d_ws;
  // ws layout (bytes) — peak 226.5 MB (R5's 236.5 MB layout ran in-bounds)
  bfraw* Wcat1 = (bfraw*)(ws + 0);            // 4 MB   [4096][512]
  bfraw* Whh1  = (bfraw*)(ws + 4194304);      // 4 MB   [2][2048][512]
  bfraw* Wcat2 = (bfraw*)(ws + 8388608);      // 8 MB   [4096][1024]
  bfraw* Whh2  = (bfraw*)(ws + 16777216);     // 4 MB
  bfraw* fcW   = (bfraw*)(ws + 20971520);     // 256 KB [128][1024]
  float* bias1 = (float*)(ws + 21233664);     // 16 KB
  float* bias2 = (float*)(ws + 21250048);     // 16 KB
  float* fcb   = (float*)(ws + 21266432);     // 512 B
  int*   bar   = (int*)(ws + 21266944);       // 64 B barrier counters [4]
  bfraw* out1  = (bfraw*)(ws + 22020096);     // 33.5 MB [16384][1024]
  bfraw* out2  = (bfraw*)(ws + 56623104);     // 33.5 MB (xs aliases first 16.8 MB)
  bfraw* xs    = out2;                        // 16.8 MB [16384][512] — dead before out2 writes
  bfraw* G     = (bfraw*)(ws + 92274688);     // 134.2 MB [16384][4096] full-T
  float* outp  = (float*)d_out;               // FP32 logits [B][T][50]

  hipMemsetAsync(bar, 0, 64, stream);   // zero barrier counters (ws is poisoned 0xAA)

  auto cvt = [&](const float* s, bfraw* dp, int n) {
    k_cvt<<<(n + 255) / 256, 256, 0, stream>>>(s, dp, n);
  };
  cvt(Wih_f1, Wcat1, 2048 * 512);
  cvt(Wih_b1, Wcat1 + 2048 * 512, 2048 * 512);
  cvt(Whh_f1, Whh1, 2048 * 512);
  cvt(Whh_b1, Whh1 + 2048 * 512, 2048 * 512);
  cvt(Wih_f2, Wcat2, 2048 * 1024);
  cvt(Wih_b2, Wcat2 + 2048 * 1024, 2048 * 1024);
  cvt(Whh_f2, Whh2, 2048 * 512);
  cvt(Whh_b2, Whh2 + 2048 * 512, 2048 * 512);
  k_bias<<<8, 256, 0, stream>>>(bih_f1, bhh_f1, bias1, 2048);
  k_bias<<<8, 256, 0, stream>>>(bih_b1, bhh_b1, bias1 + 2048, 2048);
  k_bias<<<8, 256, 0, stream>>>(bih_f2, bhh_f2, bias2, 2048);
  k_bias<<<8, 256, 0, stream>>>(bih_b2, bhh_b2, bias2 + 2048, 2048);
  k_fcpad<<<512, 256, 0, stream>>>(fc_W, fc_b, fcW, fcb);

  k_embed<<<4096, 256, 0, stream>>>(x, emb, xs);

  // layer 1: gate GEMMs (full T, fw + bw) then persistent recurrence
  k_gemm<0><<<dim3(128, 16), 256, 0, stream>>>(xs, Wcat1, bias1, G, 512, 4096);
  k_gemm<0><<<dim3(128, 16), 256, 0, stream>>>(xs, Wcat1 + 2048 * 512, bias1 + 2048,
                                               G + 2048, 512, 4096);
  k_lstm_seq<<<64, 256, 0, stream>>>(G, Whh1, out1, bar);

  // layer 2
  k_gemm<0><<<dim3(128, 16), 256, 0, stream>>>(out1, Wcat2, bias2, G, 1024, 4096);
  k_gemm<0><<<dim3(128, 16), 256, 0, stream>>>(out1, Wcat2 + (size_t)2048 * 1024,
                                               bias2 + 2048, G + 2048, 1024, 4096);
  k_lstm_seq<<<64, 256, 0, stream>>>(G, Whh2, out2, bar + 2);

  // FC -> FP32 logits [B][T][50]
  k_gemm<1><<<dim3(128, 1), 256, 0, stream>>>(out2, fcW, fcb, outp, 1024, 0);
}